// Round 12
// baseline (850.500 us; speedup 1.0000x reference)
//
#include <hip/hip_runtime.h>
#include <math.h>

// ---------------------------------------------------------------------------
// GeometricAttentionLayer: B=2, N=2048, C=64, MV=16, D=64, H=8, BLADE=9
// R12: R11 hybrid (split=16x16x32 conflict-free, value=32x32x16) + merged
// both-batch O-projection (A2 [4096,8192], one split-K=4 dispatch @1024
// blocks, Part aliases Pf region) + single reduce4.
// ---------------------------------------------------------------------------

typedef __bf16 bf16x8 __attribute__((ext_vector_type(8)));
typedef __bf16 bf16x4 __attribute__((ext_vector_type(4)));
typedef float floatx4 __attribute__((ext_vector_type(4)));
typedef float floatx16 __attribute__((ext_vector_type(16)));

__constant__ int c_ip[8] = {0, 2, 3, 4, 8, 9, 10, 14};

// ---------------------------------------------------------------------------
// prep2: one block per output row (coalesced, LDS-staged weights).
// ---------------------------------------------------------------------------
__global__ __launch_bounds__(256) void prep2(
    const float* __restrict__ x, const float* __restrict__ blade,
    const float* __restrict__ w_q, const float* __restrict__ w_k,
    const float* __restrict__ w_v, const float* __restrict__ w_o,
    __bf16* __restrict__ xh, __bf16* __restrict__ xl,
    __bf16* __restrict__ wbqkh, __bf16* __restrict__ wbqkl,
    __bf16* __restrict__ wbv, __bf16* __restrict__ wbo)
{
  __shared__ float sw[4608];
  __shared__ float sbl[144];
  const int blk = blockIdx.x;
  const int tid = threadIdx.x;

  if (blk < 4608) {            // ---- wbqk row (hi/lo) ----
    int n = blk;
    const float* wrow;
    int y;
    if (n < 4096) {            // q rows: n = h*512 + d*8 + e ; j = d*8+h
      int e = n & 7, d = (n >> 3) & 63, h = n >> 9;
      wrow = w_q + (size_t)(d * 8 + h) * 576;
      y = c_ip[e];
    } else {                   // k rows: n-4096 = d*8 + e ; j = d
      int n2 = n - 4096;
      int e = n2 & 7, d = n2 >> 3;
      wrow = w_k + (size_t)d * 576;
      y = c_ip[e];
    }
    for (int t = tid; t < 576; t += 256) sw[t] = wrow[t];
    if (tid < 144) sbl[tid] = blade[(tid >> 4) * 256 + (tid & 15) * 16 + y];
    __syncthreads();
#pragma unroll
    for (int kq = 0; kq < 4; kq++) {
      int k = kq * 256 + tid;            // k = i*16 + x
      int i = k >> 4, xx = k & 15;
      float s = 0.f;
#pragma unroll
      for (int b = 0; b < 9; b++) s += sw[i * 9 + b] * sbl[b * 16 + xx];
      __bf16 h16 = (__bf16)s;
      wbqkh[(size_t)n * 1024 + k] = h16;
      wbqkl[(size_t)n * 1024 + k] = (__bf16)(s - (float)h16);
    }
  } else if (blk < 5632) {     // ---- wbv row ----
    int n = blk - 4608;        // n = d*16 + mv ; y = mv
    int d = n >> 4, y = n & 15;
    const float* wrow = w_v + (size_t)d * 576;
    for (int t = tid; t < 576; t += 256) sw[t] = wrow[t];
    if (tid < 144) sbl[tid] = blade[(tid >> 4) * 256 + (tid & 15) * 16 + y];
    __syncthreads();
#pragma unroll
    for (int kq = 0; kq < 4; kq++) {
      int k = kq * 256 + tid;
      int i = k >> 4, xx = k & 15;
      float s = 0.f;
#pragma unroll
      for (int b = 0; b < 9; b++) s += sw[i * 9 + b] * sbl[b * 16 + xx];
      wbv[(size_t)n * 1024 + k] = (__bf16)s;
    }
  } else if (blk < 6656) {     // ---- wbo row ----
    int n = blk - 5632;        // n = c*16 + y
    int c = n >> 4, y = n & 15;
    const float* wrow = w_o + (size_t)c * 4608;   // w_o[c, ich, b]
    for (int t = tid; t < 4608; t += 256) sw[t] = wrow[t];
    if (tid < 144) sbl[tid] = blade[(tid >> 4) * 256 + (tid & 15) * 16 + y];
    __syncthreads();
#pragma unroll
    for (int kq = 0; kq < 32; kq++) {
      int k = kq * 256 + tid;            // k = h*1024 + d*16 + mv
      int ich = (k >> 10) * 64 + ((k >> 4) & 63);
      int mv = k & 15;
      float s = 0.f;
#pragma unroll
      for (int b = 0; b < 9; b++) s += sw[ich * 9 + b] * sbl[b * 16 + mv];
      wbo[(size_t)n * 8192 + k] = (__bf16)s;
    }
  } else {                     // ---- x split (float4) ----
    int idx = (blk - 6656) * 256 + tid;  // over 4096*1024/4
    float4 v = ((const float4*)x)[idx];
    bf16x4 h, l;
    h.x = (__bf16)v.x; l.x = (__bf16)(v.x - (float)h.x);
    h.y = (__bf16)v.y; l.y = (__bf16)(v.y - (float)h.y);
    h.z = (__bf16)v.z; l.z = (__bf16)(v.z - (float)h.z);
    h.w = (__bf16)v.w; l.w = (__bf16)(v.w - (float)h.w);
    *(bf16x4*)(xh + (size_t)idx * 4) = h;
    *(bf16x4*)(xl + (size_t)idx * 4) = l;
  }
}

// sum 4 partial f32 buffers (each n elements) into out
__global__ __launch_bounds__(256) void reduce4(
    const float* __restrict__ p, float* __restrict__ out, int n)
{
  int i = (blockIdx.x * 256 + threadIdx.x) * 4;
  if (i >= n) return;
  float4 a = *(const float4*)(p + i);
  float4 b = *(const float4*)(p + (size_t)n + i);
  float4 c = *(const float4*)(p + 2 * (size_t)n + i);
  float4 d = *(const float4*)(p + 3 * (size_t)n + i);
  *(float4*)(out + i) = make_float4(a.x + b.x + c.x + d.x, a.y + b.y + c.y + d.y,
                                    a.z + b.z + c.z + d.z, a.w + b.w + c.w + d.w);
}

// ---------------------------------------------------------------------------
static __device__ __forceinline__ void gll16(const __bf16* g, __bf16* l) {
  __builtin_amdgcn_global_load_lds(
      (const __attribute__((address_space(1))) void*)g,
      (__attribute__((address_space(3))) void*)l, 16, 0, 0);
}

// GROUP_M=4 panel swizzle (L2 locality).
static __device__ __forceinline__ void swizzle_mn(int& m0, int& n0) {
  int gn = gridDim.x;
  int flat = blockIdx.y * gn + blockIdx.x;
  int panel = flat / (4 * gn);
  int r = flat - panel * 4 * gn;
  m0 = (panel * 4 + (r & 3)) * 128;
  n0 = (r >> 2) * 128;
}

// LDS slot of (row, logical k16-step t, k-half kh) under the staging swizzle.
static __device__ __forceinline__ int frag_off32(int row, int t, int kh) {
  return row * 32 + 8 * ((2 * t + kh) ^ ((row >> 1) & 3));
}

// ---------------------------------------------------------------------------
// Plain bf16 MFMA GEMM (32x32x16): C = alpha * A * Bt^T. 128x128, BK=32.
// EPI: 0 = f32 store, 3 = bf16 store. z-batched via element strides.
// ---------------------------------------------------------------------------
template <int EPI>
__global__ __launch_bounds__(256) void gemm_bf16(
    const __bf16* __restrict__ A, int lda, long long sAz,
    const __bf16* __restrict__ Bt, int ldb, long long sBz,
    void* __restrict__ C0v, int ldc, long long sCz,
    int K, float alpha)
{
  __shared__ __bf16 As[128 * 32];
  __shared__ __bf16 Bs[128 * 32];
  const int tid = threadIdx.x;
  const int wave = tid >> 6, lane = tid & 63;
  int m0, n0;
  swizzle_mn(m0, n0);
  A  += (size_t)blockIdx.z * sAz;
  Bt += (size_t)blockIdx.z * sBz;

  const int srow = lane >> 2;
  const int skk = 8 * ((lane & 3) ^ ((lane >> 3) & 3));
  const __bf16* gA0 = A  + (size_t)(m0 + wave * 32      + srow) * lda + skk;
  const __bf16* gA1 = A  + (size_t)(m0 + wave * 32 + 16 + srow) * lda + skk;
  const __bf16* gB0 = Bt + (size_t)(n0 + wave * 32      + srow) * ldb + skk;
  const __bf16* gB1 = Bt + (size_t)(n0 + wave * 32 + 16 + srow) * ldb + skk;
  const int ldsoff = wave * 1024;

  const int l31 = lane & 31, kh = lane >> 5;
  const int wm = (wave & 1) * 64, wn = (wave >> 1) * 64;
  int aoff[2][2], boff[2][2];
#pragma unroll
  for (int i = 0; i < 2; i++)
#pragma unroll
    for (int t = 0; t < 2; t++) {
      aoff[i][t] = frag_off32(wm + i * 32 + l31, t, kh);
      boff[i][t] = frag_off32(wn + i * 32 + l31, t, kh);
    }

  floatx16 acc[2][2];
#pragma unroll
  for (int i = 0; i < 2; i++)
#pragma unroll
    for (int j = 0; j < 2; j++)
#pragma unroll
      for (int e = 0; e < 16; e++) acc[i][j][e] = 0.f;

  for (int k0 = 0; k0 < K; k0 += 32) {
    gll16(gA0, As + ldsoff); gll16(gA1, As + ldsoff + 512);
    gll16(gB0, Bs + ldsoff); gll16(gB1, Bs + ldsoff + 512);
    gA0 += 32; gA1 += 32; gB0 += 32; gB1 += 32;
    __syncthreads();
    bf16x8 af[2][2], bfv[2][2];
#pragma unroll
    for (int i = 0; i < 2; i++)
#pragma unroll
      for (int t = 0; t < 2; t++) {
        af[i][t]  = *(const bf16x8*)(As + aoff[i][t]);
        bfv[i][t] = *(const bf16x8*)(Bs + boff[i][t]);
      }
#pragma unroll
    for (int t = 0; t < 2; t++)
#pragma unroll
      for (int i = 0; i < 2; i++)
#pragma unroll
        for (int j = 0; j < 2; j++)
          acc[i][j] = __builtin_amdgcn_mfma_f32_32x32x16_bf16(
              af[i][t], bfv[j][t], acc[i][j], 0, 0, 0);
    __syncthreads();
  }

  // C/D: col = lane&31, row = (reg&3) + 8*(reg>>2) + 4*kh  [m74/m101]
  const int rb = m0 + wm + 4 * kh;
  const int cb = n0 + wn + l31;
#pragma unroll
  for (int i = 0; i < 2; i++) {
#pragma unroll
    for (int j = 0; j < 2; j++) {
      int c = cb + j * 32;
#pragma unroll
      for (int q = 0; q < 4; q++) {
        int r = rb + i * 32 + 8 * q;
        float v0 = acc[i][j][q * 4 + 0] * alpha;
        float v1 = acc[i][j][q * 4 + 1] * alpha;
        float v2 = acc[i][j][q * 4 + 2] * alpha;
        float v3 = acc[i][j][q * 4 + 3] * alpha;
        if (EPI == 0) {
          float* C = (float*)C0v + (size_t)blockIdx.z * sCz;
          float* p = C + (size_t)r * ldc + c;
          p[0] = v0; p[ldc] = v1; p[2 * ldc] = v2; p[3 * ldc] = v3;
        } else {  // EPI == 3: bf16 store
          __bf16* C = (__bf16*)C0v + (size_t)blockIdx.z * sCz;
          C[(size_t)r * ldc + c] = (__bf16)v0;
          C[(size_t)(r + 1) * ldc + c] = (__bf16)v1;
          C[(size_t)(r + 2) * ldc + c] = (__bf16)v2;
          C[(size_t)(r + 3) * ldc + c] = (__bf16)v3;
        }
      }
    }
  }
}

// ---------------------------------------------------------------------------
// Fused split-bf16 GEMM (16x16x32, conflict-free):
// C = alpha * (Ah*Bh^T + Al*Bh^T + Ah*Bl^T). 48 MFMA per 32-k step.
// EPI: 0 = f32 store, 2 = split hi/lo bf16 store.
// ---------------------------------------------------------------------------
template <int EPI>
__global__ __launch_bounds__(256) void gemm_split(
    const __bf16* __restrict__ Ah, const __bf16* __restrict__ Al, int lda, long long sAz,
    const __bf16* __restrict__ Bh, const __bf16* __restrict__ Bl, int ldb, long long sBz,
    void* __restrict__ C0v, void* __restrict__ C1v, int ldc, long long sCz,
    int K, float alpha)
{
  __shared__ __bf16 Ash[128 * 32];
  __shared__ __bf16 Asl[128 * 32];
  __shared__ __bf16 Bsh[128 * 32];
  __shared__ __bf16 Bsl[128 * 32];
  const int tid = threadIdx.x;
  const int wave = tid >> 6, lane = tid & 63;
  int m0, n0;
  swizzle_mn(m0, n0);
  Ah += (size_t)blockIdx.z * sAz;
  Al += (size_t)blockIdx.z * sAz;
  Bh += (size_t)blockIdx.z * sBz;
  Bl += (size_t)blockIdx.z * sBz;

  const int srow = lane >> 2;
  const int skk = 8 * ((lane & 3) ^ ((lane >> 3) & 3));
  const size_t ao0 = (size_t)(m0 + wave * 32      + srow) * lda + skk;
  const size_t ao1 = (size_t)(m0 + wave * 32 + 16 + srow) * lda + skk;
  const size_t bo0 = (size_t)(n0 + wave * 32      + srow) * ldb + skk;
  const size_t bo1 = (size_t)(n0 + wave * 32 + 16 + srow) * ldb + skk;
  const __bf16 *gAh0 = Ah + ao0, *gAh1 = Ah + ao1;
  const __bf16 *gAl0 = Al + ao0, *gAl1 = Al + ao1;
  const __bf16 *gBh0 = Bh + bo0, *gBh1 = Bh + bo1;
  const __bf16 *gBl0 = Bl + bo0, *gBl1 = Bl + bo1;
  const int ldsoff = wave * 1024;

  const int fr = lane & 15, fq = lane >> 4;
  const int wm = (wave & 1) * 64, wn = (wave >> 1) * 64;
  int aoff[4], boff[4];
#pragma unroll
  for (int t = 0; t < 4; t++) {
    int rA = wm + t * 16 + fr;
    aoff[t] = rA * 32 + 8 * (fq ^ ((rA >> 1) & 3));
    int rB = wn + t * 16 + fr;
    boff[t] = rB * 32 + 8 * (fq ^ ((rB >> 1) & 3));
  }

  floatx4 acc[4][4];
#pragma unroll
  for (int i = 0; i < 4; i++)
#pragma unroll
    for (int j = 0; j < 4; j++) acc[i][j] = (floatx4){0.f, 0.f, 0.f, 0.f};

  for (int k0 = 0; k0 < K; k0 += 32) {
    gll16(gAh0, Ash + ldsoff); gll16(gAh1, Ash + ldsoff + 512);
    gll16(gAl0, Asl + ldsoff); gll16(gAl1, Asl + ldsoff + 512);
    gll16(gBh0, Bsh + ldsoff); gll16(gBh1, Bsh + ldsoff + 512);
    gll16(gBl0, Bsl + ldsoff); gll16(gBl1, Bsl + ldsoff + 512);
    gAh0 += 32; gAh1 += 32; gAl0 += 32; gAl1 += 32;
    gBh0 += 32; gBh1 += 32; gBl0 += 32; gBl1 += 32;
    __syncthreads();
    bf16x8 afh[4], afl[4], bfh[4], bfl[4];
#pragma unroll
    for (int t = 0; t < 4; t++) {
      afh[t] = *(const bf16x8*)(Ash + aoff[t]);
      afl[t] = *(const bf16x8*)(Asl + aoff[t]);
      bfh[t] = *(const bf16x8*)(Bsh + boff[t]);
      bfl[t] = *(const bf16x8*)(Bsl + boff[t]);
    }
#pragma unroll
    for (int i = 0; i < 4; i++)
#pragma unroll
      for (int j = 0; j < 4; j++) {
        acc[i][j] = __builtin_amdgcn_mfma_f32_16x16x32_bf16(
            afh[i], bfh[j], acc[i][j], 0, 0, 0);
        acc[i][j] = __builtin_amdgcn_mfma_f32_16x16x32_bf16(
            afl[i], bfh[j], acc[i][j], 0, 0, 0);
        acc[i][j] = __builtin_amdgcn_mfma_f32_16x16x32_bf16(
            afh[i], bfl[j], acc[i][j], 0, 0, 0);
      }
    __syncthreads();
  }

  const int rb = m0 + wm + fq * 4;
  const int cb = n0 + wn + fr;
#pragma unroll
  for (int i = 0; i < 4; i++) {
#pragma unroll
    for (int j = 0; j < 4; j++) {
      float vv[4] = {acc[i][j].x * alpha, acc[i][j].y * alpha,
                     acc[i][j].z * alpha, acc[i][j].w * alpha};
      int r = rb + i * 16, c = cb + j * 16;
      if (EPI == 0) {
        float* C = (float*)C0v + (size_t)blockIdx.z * sCz;
        float* p = C + (size_t)r * ldc + c;
        p[0] = vv[0]; p[ldc] = vv[1]; p[2 * ldc] = vv[2]; p[3 * ldc] = vv[3];
      } else {  // EPI == 2: split hi/lo
        __bf16* Hp = (__bf16*)C0v + (size_t)blockIdx.z * sCz;
        __bf16* Lp = (__bf16*)C1v + (size_t)blockIdx.z * sCz;
#pragma unroll
        for (int t = 0; t < 4; t++) {
          size_t o = (size_t)(r + t) * ldc + c;
          __bf16 hh = (__bf16)vv[t];
          Hp[o] = hh;
          Lp[o] = (__bf16)(vv[t] - (float)hh);
        }
      }
    }
  }
}

// ---------------------------------------------------------------------------
// Wave-per-row in-place softmax: f32 row [2048] -> bf16 into same row.
// ---------------------------------------------------------------------------
__global__ __launch_bounds__(256) void softmax_wave(float* __restrict__ Pf)
{
  const int wave = threadIdx.x >> 6, lane = threadIdx.x & 63;
  const size_t row = (size_t)blockIdx.x * 4 + wave;
  float* p = Pf + row * 2048;
  __bf16* q = (__bf16*)p;

  float4 v[8];
  float m = -1e30f;
#pragma unroll
  for (int t = 0; t < 8; t++) {
    v[t] = ((const float4*)p)[lane + t * 64];
    m = fmaxf(m, fmaxf(fmaxf(v[t].x, v[t].y), fmaxf(v[t].z, v[t].w)));
  }
#pragma unroll
  for (int off = 32; off; off >>= 1) m = fmaxf(m, __shfl_xor(m, off, 64));

  float s = 0.f;
#pragma unroll
  for (int t = 0; t < 8; t++) {
    v[t].x = expf(v[t].x - m); v[t].y = expf(v[t].y - m);
    v[t].z = expf(v[t].z - m); v[t].w = expf(v[t].w - m);
    s += (v[t].x + v[t].y) + (v[t].z + v[t].w);
  }
#pragma unroll
  for (int off = 32; off; off >>= 1) s += __shfl_xor(s, off, 64);
  float inv = 1.0f / s;

#pragma unroll
  for (int t = 0; t < 8; t++) {
    bf16x4 o;
    o.x = (__bf16)(v[t].x * inv); o.y = (__bf16)(v[t].y * inv);
    o.z = (__bf16)(v[t].z * inv); o.w = (__bf16)(v[t].w * inv);
    *(bf16x4*)(q + (lane + t * 64) * 4) = o;
  }
}

// ---------------------------------------------------------------------------
extern "C" void kernel_launch(void* const* d_in, const int* in_sizes, int n_in,
                              void* d_out, int out_size, void* d_ws, size_t ws_size,
                              hipStream_t stream)
{
  (void)in_sizes; (void)n_in; (void)out_size; (void)ws_size;
  const float* x     = (const float*)d_in[0];
  const float* blade = (const float*)d_in[1];
  const float* w_q   = (const float*)d_in[2];
  const float* w_k   = (const float*)d_in[3];
  const float* w_v   = (const float*)d_in[4];
  const float* w_o   = (const float*)d_in[5];
  float* out = (float*)d_out;

  // --- fixed aliased workspace plan (peak 224 MiB; ws >= 256 MB) -----------
  char* base = (char*)d_ws;
  __bf16* wbo   = (__bf16*)(base);                  //  16.78 MB [1024,8192]
  __bf16* vT    = (__bf16*)(base + 16777216);       //   8.39 MB [1024,4096]
  __bf16* qkmh  = (__bf16*)(base + 25165824);       //  37.75 MB [4096,4608]
  __bf16* qkml  = (__bf16*)(base + 62914560);       //  37.75 MB
  char* scr = base + 100663296;
  // phase 1 (aliases Pf region):
  __bf16* xh    = (__bf16*)(scr);                   //   8.39 MB [4096,1024]
  __bf16* xl    = (__bf16*)(scr + 8388608);         //   8.39 MB
  __bf16* wbqkh = (__bf16*)(scr + 16777216);        //   9.44 MB [4608,1024]
  __bf16* wbqkl = (__bf16*)(scr + 26214400);        //   9.44 MB
  __bf16* wbv   = (__bf16*)(scr + 35651584);        //   2.10 MB [1024,1024]
  // phase 2: Pf [4,2048,2048] f32; A2 [4096,8192] bf16 (BOTH batches)
  float*  Pf    = (float*)(scr);                    //  67.11 MB
  __bf16* A2    = (__bf16*)(scr + 67108864);        //  67.11 MB
  // phase 3: Part aliases Pf (all PV reads of Pf precede O-proj in-stream)
  float*  Part  = (float*)(scr);                    //  67.11 MB [4,4096,1024]

  dim3 blk(256);
  const float scale = 0.04419417382415922f;  // 1/sqrt(512)

  // --- phase 1: prep + projections ----------------------------------------
  prep2<<<10752, blk, 0, stream>>>(x, blade, w_q, w_k, w_v, w_o,
                                   xh, xl, wbqkh, wbqkl, wbv, wbo);

  // qkm = [q | km] hi/lo: [4096,1024] x [4608,1024]^T -> [4096,4608]
  gemm_split<2><<<dim3(36, 32, 1), blk, 0, stream>>>(
      xh, xl, 1024, 0, wbqkh, wbqkl, 1024, 0, qkmh, qkml, 4608, 0, 1024, 1.f);

  // vT = wbv * xh^T : [1024,1024] x [4096,1024]^T -> [1024,4096] bf16
  gemm_bf16<3><<<dim3(32, 8, 1), blk, 0, stream>>>(
      wbv, 1024, 0, xh, 1024, 0, vT, 4096, 0, 1024, 1.f);

  // --- phase 2: attention per batch/head-group -----------------------------
  for (int b = 0; b < 2; b++) {
    const __bf16* qh_b  = qkmh + (size_t)b * 2048 * 4608;
    const __bf16* ql_b  = qkml + (size_t)b * 2048 * 4608;
    const __bf16* kmh_b = qh_b + 4096;   // km cols 4096..4607, ldb 4608
    const __bf16* kml_b = ql_b + 4096;

    for (int h0 = 0; h0 < 8; h0 += 4) {
      // scores -> Pf [z,2048,2048] f32 (z = head in group)
      gemm_split<0><<<dim3(16, 16, 4), blk, 0, stream>>>(
          qh_b + h0 * 512, ql_b + h0 * 512, 4608, 512,
          kmh_b, kml_b, 4608, 0,
          Pf, nullptr, 2048, (long long)2048 * 2048, 512, scale);
      // softmax in place: bf16 P into Pf rows (row stride 4096 bf16 units)
      softmax_wave<<<4 * 2048 / 4, blk, 0, stream>>>(Pf);
      // PV: P [z,2048,2048] * vT_b^T -> A2[b] cols (h0+z)*1024
      gemm_bf16<3><<<dim3(8, 16, 4), blk, 0, stream>>>(
          (const __bf16*)Pf, 4096, (long long)2048 * 4096,
          vT + (size_t)b * 2048, 4096, 0,
          A2 + (size_t)b * 2048 * 8192 + (size_t)h0 * 1024, 8192, 1024,
          2048, 1.f);
    }
  }

  // --- phase 3: both-batch O-projection, split-K=4 -> partials -> out ------
  gemm_bf16<0><<<dim3(8, 32, 4), blk, 0, stream>>>(
      A2, 8192, 2048, wbo, 8192, 2048,
      Part, 1024, (long long)4096 * 1024, 2048, 1.f);
  reduce4<<<4096, blk, 0, stream>>>(Part, out, 4096 * 1024);
}

// Round 13
// 831.223 us; speedup vs baseline: 1.0232x; 1.0232x over previous
//
#include <hip/hip_runtime.h>
#include <math.h>

// ---------------------------------------------------------------------------
// GeometricAttentionLayer: B=2, N=2048, C=64, MV=16, D=64, H=8, BLADE=9
// R13: R11 structure (per-batch O-proj — R12's merged version lost L2
// producer->consumer locality, -16us) + GROUP=8 panel swizzle on gemm_split
// (qkm FETCH 127 MB vs 36 compulsory: halve B re-sweeps). gemm_bf16 keeps
// GROUP=4. split=16x16x32 (conflict-free), value=32x32x16.
// ---------------------------------------------------------------------------

typedef __bf16 bf16x8 __attribute__((ext_vector_type(8)));
typedef __bf16 bf16x4 __attribute__((ext_vector_type(4)));
typedef float floatx4 __attribute__((ext_vector_type(4)));
typedef float floatx16 __attribute__((ext_vector_type(16)));

__constant__ int c_ip[8] = {0, 2, 3, 4, 8, 9, 10, 14};

// ---------------------------------------------------------------------------
// prep2: one block per output row (coalesced, LDS-staged weights).
// ---------------------------------------------------------------------------
__global__ __launch_bounds__(256) void prep2(
    const float* __restrict__ x, const float* __restrict__ blade,
    const float* __restrict__ w_q, const float* __restrict__ w_k,
    const float* __restrict__ w_v, const float* __restrict__ w_o,
    __bf16* __restrict__ xh, __bf16* __restrict__ xl,
    __bf16* __restrict__ wbqkh, __bf16* __restrict__ wbqkl,
    __bf16* __restrict__ wbv, __bf16* __restrict__ wbo)
{
  __shared__ float sw[4608];
  __shared__ float sbl[144];
  const int blk = blockIdx.x;
  const int tid = threadIdx.x;

  if (blk < 4608) {            // ---- wbqk row (hi/lo) ----
    int n = blk;
    const float* wrow;
    int y;
    if (n < 4096) {            // q rows: n = h*512 + d*8 + e ; j = d*8+h
      int e = n & 7, d = (n >> 3) & 63, h = n >> 9;
      wrow = w_q + (size_t)(d * 8 + h) * 576;
      y = c_ip[e];
    } else {                   // k rows: n-4096 = d*8 + e ; j = d
      int n2 = n - 4096;
      int e = n2 & 7, d = n2 >> 3;
      wrow = w_k + (size_t)d * 576;
      y = c_ip[e];
    }
    for (int t = tid; t < 576; t += 256) sw[t] = wrow[t];
    if (tid < 144) sbl[tid] = blade[(tid >> 4) * 256 + (tid & 15) * 16 + y];
    __syncthreads();
#pragma unroll
    for (int kq = 0; kq < 4; kq++) {
      int k = kq * 256 + tid;            // k = i*16 + x
      int i = k >> 4, xx = k & 15;
      float s = 0.f;
#pragma unroll
      for (int b = 0; b < 9; b++) s += sw[i * 9 + b] * sbl[b * 16 + xx];
      __bf16 h16 = (__bf16)s;
      wbqkh[(size_t)n * 1024 + k] = h16;
      wbqkl[(size_t)n * 1024 + k] = (__bf16)(s - (float)h16);
    }
  } else if (blk < 5632) {     // ---- wbv row ----
    int n = blk - 4608;        // n = d*16 + mv ; y = mv
    int d = n >> 4, y = n & 15;
    const float* wrow = w_v + (size_t)d * 576;
    for (int t = tid; t < 576; t += 256) sw[t] = wrow[t];
    if (tid < 144) sbl[tid] = blade[(tid >> 4) * 256 + (tid & 15) * 16 + y];
    __syncthreads();
#pragma unroll
    for (int kq = 0; kq < 4; kq++) {
      int k = kq * 256 + tid;
      int i = k >> 4, xx = k & 15;
      float s = 0.f;
#pragma unroll
      for (int b = 0; b < 9; b++) s += sw[i * 9 + b] * sbl[b * 16 + xx];
      wbv[(size_t)n * 1024 + k] = (__bf16)s;
    }
  } else if (blk < 6656) {     // ---- wbo row ----
    int n = blk - 5632;        // n = c*16 + y
    int c = n >> 4, y = n & 15;
    const float* wrow = w_o + (size_t)c * 4608;   // w_o[c, ich, b]
    for (int t = tid; t < 4608; t += 256) sw[t] = wrow[t];
    if (tid < 144) sbl[tid] = blade[(tid >> 4) * 256 + (tid & 15) * 16 + y];
    __syncthreads();
#pragma unroll
    for (int kq = 0; kq < 32; kq++) {
      int k = kq * 256 + tid;            // k = h*1024 + d*16 + mv
      int ich = (k >> 10) * 64 + ((k >> 4) & 63);
      int mv = k & 15;
      float s = 0.f;
#pragma unroll
      for (int b = 0; b < 9; b++) s += sw[ich * 9 + b] * sbl[b * 16 + mv];
      wbo[(size_t)n * 8192 + k] = (__bf16)s;
    }
  } else {                     // ---- x split (float4) ----
    int idx = (blk - 6656) * 256 + tid;  // over 4096*1024/4
    float4 v = ((const float4*)x)[idx];
    bf16x4 h, l;
    h.x = (__bf16)v.x; l.x = (__bf16)(v.x - (float)h.x);
    h.y = (__bf16)v.y; l.y = (__bf16)(v.y - (float)h.y);
    h.z = (__bf16)v.z; l.z = (__bf16)(v.z - (float)h.z);
    h.w = (__bf16)v.w; l.w = (__bf16)(v.w - (float)h.w);
    *(bf16x4*)(xh + (size_t)idx * 4) = h;
    *(bf16x4*)(xl + (size_t)idx * 4) = l;
  }
}

// sum 4 partial f32 buffers (each n elements) into out
__global__ __launch_bounds__(256) void reduce4(
    const float* __restrict__ p, float* __restrict__ out, int n)
{
  int i = (blockIdx.x * 256 + threadIdx.x) * 4;
  if (i >= n) return;
  float4 a = *(const float4*)(p + i);
  float4 b = *(const float4*)(p + (size_t)n + i);
  float4 c = *(const float4*)(p + 2 * (size_t)n + i);
  float4 d = *(const float4*)(p + 3 * (size_t)n + i);
  *(float4*)(out + i) = make_float4(a.x + b.x + c.x + d.x, a.y + b.y + c.y + d.y,
                                    a.z + b.z + c.z + d.z, a.w + b.w + c.w + d.w);
}

// ---------------------------------------------------------------------------
static __device__ __forceinline__ void gll16(const __bf16* g, __bf16* l) {
  __builtin_amdgcn_global_load_lds(
      (const __attribute__((address_space(1))) void*)g,
      (__attribute__((address_space(3))) void*)l, 16, 0, 0);
}

// GROUP-panel swizzle (L2 locality). Requires gridDim.y % GROUP == 0.
template <int GROUP>
static __device__ __forceinline__ void swizzle_mn(int& m0, int& n0) {
  int gn = gridDim.x;
  int flat = blockIdx.y * gn + blockIdx.x;
  int panel = flat / (GROUP * gn);
  int r = flat - panel * GROUP * gn;
  m0 = (panel * GROUP + (r % GROUP)) * 128;
  n0 = (r / GROUP) * 128;
}

// LDS slot of (row, logical k16-step t, k-half kh) under the staging swizzle.
static __device__ __forceinline__ int frag_off32(int row, int t, int kh) {
  return row * 32 + 8 * ((2 * t + kh) ^ ((row >> 1) & 3));
}

// ---------------------------------------------------------------------------
// Plain bf16 MFMA GEMM (32x32x16): C = alpha * A * Bt^T. 128x128, BK=32.
// EPI: 0 = f32 store, 3 = bf16 store. z-batched via element strides.
// ---------------------------------------------------------------------------
template <int EPI>
__global__ __launch_bounds__(256) void gemm_bf16(
    const __bf16* __restrict__ A, int lda, long long sAz,
    const __bf16* __restrict__ Bt, int ldb, long long sBz,
    void* __restrict__ C0v, int ldc, long long sCz,
    int K, float alpha)
{
  __shared__ __bf16 As[128 * 32];
  __shared__ __bf16 Bs[128 * 32];
  const int tid = threadIdx.x;
  const int wave = tid >> 6, lane = tid & 63;
  int m0, n0;
  swizzle_mn<4>(m0, n0);
  A  += (size_t)blockIdx.z * sAz;
  Bt += (size_t)blockIdx.z * sBz;

  const int srow = lane >> 2;
  const int skk = 8 * ((lane & 3) ^ ((lane >> 3) & 3));
  const __bf16* gA0 = A  + (size_t)(m0 + wave * 32      + srow) * lda + skk;
  const __bf16* gA1 = A  + (size_t)(m0 + wave * 32 + 16 + srow) * lda + skk;
  const __bf16* gB0 = Bt + (size_t)(n0 + wave * 32      + srow) * ldb + skk;
  const __bf16* gB1 = Bt + (size_t)(n0 + wave * 32 + 16 + srow) * ldb + skk;
  const int ldsoff = wave * 1024;

  const int l31 = lane & 31, kh = lane >> 5;
  const int wm = (wave & 1) * 64, wn = (wave >> 1) * 64;
  int aoff[2][2], boff[2][2];
#pragma unroll
  for (int i = 0; i < 2; i++)
#pragma unroll
    for (int t = 0; t < 2; t++) {
      aoff[i][t] = frag_off32(wm + i * 32 + l31, t, kh);
      boff[i][t] = frag_off32(wn + i * 32 + l31, t, kh);
    }

  floatx16 acc[2][2];
#pragma unroll
  for (int i = 0; i < 2; i++)
#pragma unroll
    for (int j = 0; j < 2; j++)
#pragma unroll
      for (int e = 0; e < 16; e++) acc[i][j][e] = 0.f;

  for (int k0 = 0; k0 < K; k0 += 32) {
    gll16(gA0, As + ldsoff); gll16(gA1, As + ldsoff + 512);
    gll16(gB0, Bs + ldsoff); gll16(gB1, Bs + ldsoff + 512);
    gA0 += 32; gA1 += 32; gB0 += 32; gB1 += 32;
    __syncthreads();
    bf16x8 af[2][2], bfv[2][2];
#pragma unroll
    for (int i = 0; i < 2; i++)
#pragma unroll
      for (int t = 0; t < 2; t++) {
        af[i][t]  = *(const bf16x8*)(As + aoff[i][t]);
        bfv[i][t] = *(const bf16x8*)(Bs + boff[i][t]);
      }
#pragma unroll
    for (int t = 0; t < 2; t++)
#pragma unroll
      for (int i = 0; i < 2; i++)
#pragma unroll
        for (int j = 0; j < 2; j++)
          acc[i][j] = __builtin_amdgcn_mfma_f32_32x32x16_bf16(
              af[i][t], bfv[j][t], acc[i][j], 0, 0, 0);
    __syncthreads();
  }

  // C/D: col = lane&31, row = (reg&3) + 8*(reg>>2) + 4*kh  [m74/m101]
  const int rb = m0 + wm + 4 * kh;
  const int cb = n0 + wn + l31;
#pragma unroll
  for (int i = 0; i < 2; i++) {
#pragma unroll
    for (int j = 0; j < 2; j++) {
      int c = cb + j * 32;
#pragma unroll
      for (int q = 0; q < 4; q++) {
        int r = rb + i * 32 + 8 * q;
        float v0 = acc[i][j][q * 4 + 0] * alpha;
        float v1 = acc[i][j][q * 4 + 1] * alpha;
        float v2 = acc[i][j][q * 4 + 2] * alpha;
        float v3 = acc[i][j][q * 4 + 3] * alpha;
        if (EPI == 0) {
          float* C = (float*)C0v + (size_t)blockIdx.z * sCz;
          float* p = C + (size_t)r * ldc + c;
          p[0] = v0; p[ldc] = v1; p[2 * ldc] = v2; p[3 * ldc] = v3;
        } else {  // EPI == 3: bf16 store
          __bf16* C = (__bf16*)C0v + (size_t)blockIdx.z * sCz;
          C[(size_t)r * ldc + c] = (__bf16)v0;
          C[(size_t)(r + 1) * ldc + c] = (__bf16)v1;
          C[(size_t)(r + 2) * ldc + c] = (__bf16)v2;
          C[(size_t)(r + 3) * ldc + c] = (__bf16)v3;
        }
      }
    }
  }
}

// ---------------------------------------------------------------------------
// Fused split-bf16 GEMM (16x16x32, conflict-free):
// C = alpha * (Ah*Bh^T + Al*Bh^T + Ah*Bl^T). 48 MFMA per 32-k step.
// EPI: 0 = f32 store, 2 = split hi/lo bf16 store. GROUP=8 swizzle.
// ---------------------------------------------------------------------------
template <int EPI>
__global__ __launch_bounds__(256) void gemm_split(
    const __bf16* __restrict__ Ah, const __bf16* __restrict__ Al, int lda, long long sAz,
    const __bf16* __restrict__ Bh, const __bf16* __restrict__ Bl, int ldb, long long sBz,
    void* __restrict__ C0v, void* __restrict__ C1v, int ldc, long long sCz,
    int K, float alpha)
{
  __shared__ __bf16 Ash[128 * 32];
  __shared__ __bf16 Asl[128 * 32];
  __shared__ __bf16 Bsh[128 * 32];
  __shared__ __bf16 Bsl[128 * 32];
  const int tid = threadIdx.x;
  const int wave = tid >> 6, lane = tid & 63;
  int m0, n0;
  swizzle_mn<8>(m0, n0);
  Ah += (size_t)blockIdx.z * sAz;
  Al += (size_t)blockIdx.z * sAz;
  Bh += (size_t)blockIdx.z * sBz;
  Bl += (size_t)blockIdx.z * sBz;

  const int srow = lane >> 2;
  const int skk = 8 * ((lane & 3) ^ ((lane >> 3) & 3));
  const size_t ao0 = (size_t)(m0 + wave * 32      + srow) * lda + skk;
  const size_t ao1 = (size_t)(m0 + wave * 32 + 16 + srow) * lda + skk;
  const size_t bo0 = (size_t)(n0 + wave * 32      + srow) * ldb + skk;
  const size_t bo1 = (size_t)(n0 + wave * 32 + 16 + srow) * ldb + skk;
  const __bf16 *gAh0 = Ah + ao0, *gAh1 = Ah + ao1;
  const __bf16 *gAl0 = Al + ao0, *gAl1 = Al + ao1;
  const __bf16 *gBh0 = Bh + bo0, *gBh1 = Bh + bo1;
  const __bf16 *gBl0 = Bl + bo0, *gBl1 = Bl + bo1;
  const int ldsoff = wave * 1024;

  const int fr = lane & 15, fq = lane >> 4;
  const int wm = (wave & 1) * 64, wn = (wave >> 1) * 64;
  int aoff[4], boff[4];
#pragma unroll
  for (int t = 0; t < 4; t++) {
    int rA = wm + t * 16 + fr;
    aoff[t] = rA * 32 + 8 * (fq ^ ((rA >> 1) & 3));
    int rB = wn + t * 16 + fr;
    boff[t] = rB * 32 + 8 * (fq ^ ((rB >> 1) & 3));
  }

  floatx4 acc[4][4];
#pragma unroll
  for (int i = 0; i < 4; i++)
#pragma unroll
    for (int j = 0; j < 4; j++) acc[i][j] = (floatx4){0.f, 0.f, 0.f, 0.f};

  for (int k0 = 0; k0 < K; k0 += 32) {
    gll16(gAh0, Ash + ldsoff); gll16(gAh1, Ash + ldsoff + 512);
    gll16(gAl0, Asl + ldsoff); gll16(gAl1, Asl + ldsoff + 512);
    gll16(gBh0, Bsh + ldsoff); gll16(gBh1, Bsh + ldsoff + 512);
    gll16(gBl0, Bsl + ldsoff); gll16(gBl1, Bsl + ldsoff + 512);
    gAh0 += 32; gAh1 += 32; gAl0 += 32; gAl1 += 32;
    gBh0 += 32; gBh1 += 32; gBl0 += 32; gBl1 += 32;
    __syncthreads();
    bf16x8 afh[4], afl[4], bfh[4], bfl[4];
#pragma unroll
    for (int t = 0; t < 4; t++) {
      afh[t] = *(const bf16x8*)(Ash + aoff[t]);
      afl[t] = *(const bf16x8*)(Asl + aoff[t]);
      bfh[t] = *(const bf16x8*)(Bsh + boff[t]);
      bfl[t] = *(const bf16x8*)(Bsl + boff[t]);
    }
#pragma unroll
    for (int i = 0; i < 4; i++)
#pragma unroll
      for (int j = 0; j < 4; j++) {
        acc[i][j] = __builtin_amdgcn_mfma_f32_16x16x32_bf16(
            afh[i], bfh[j], acc[i][j], 0, 0, 0);
        acc[i][j] = __builtin_amdgcn_mfma_f32_16x16x32_bf16(
            afl[i], bfh[j], acc[i][j], 0, 0, 0);
        acc[i][j] = __builtin_amdgcn_mfma_f32_16x16x32_bf16(
            afh[i], bfl[j], acc[i][j], 0, 0, 0);
      }
    __syncthreads();
  }

  const int rb = m0 + wm + fq * 4;
  const int cb = n0 + wn + fr;
#pragma unroll
  for (int i = 0; i < 4; i++) {
#pragma unroll
    for (int j = 0; j < 4; j++) {
      float vv[4] = {acc[i][j].x * alpha, acc[i][j].y * alpha,
                     acc[i][j].z * alpha, acc[i][j].w * alpha};
      int r = rb + i * 16, c = cb + j * 16;
      if (EPI == 0) {
        float* C = (float*)C0v + (size_t)blockIdx.z * sCz;
        float* p = C + (size_t)r * ldc + c;
        p[0] = vv[0]; p[ldc] = vv[1]; p[2 * ldc] = vv[2]; p[3 * ldc] = vv[3];
      } else {  // EPI == 2: split hi/lo
        __bf16* Hp = (__bf16*)C0v + (size_t)blockIdx.z * sCz;
        __bf16* Lp = (__bf16*)C1v + (size_t)blockIdx.z * sCz;
#pragma unroll
        for (int t = 0; t < 4; t++) {
          size_t o = (size_t)(r + t) * ldc + c;
          __bf16 hh = (__bf16)vv[t];
          Hp[o] = hh;
          Lp[o] = (__bf16)(vv[t] - (float)hh);
        }
      }
    }
  }
}

// ---------------------------------------------------------------------------
// Wave-per-row in-place softmax: f32 row [2048] -> bf16 into same row.
// ---------------------------------------------------------------------------
__global__ __launch_bounds__(256) void softmax_wave(float* __restrict__ Pf)
{
  const int wave = threadIdx.x >> 6, lane = threadIdx.x & 63;
  const size_t row = (size_t)blockIdx.x * 4 + wave;
  float* p = Pf + row * 2048;
  __bf16* q = (__bf16*)p;

  float4 v[8];
  float m = -1e30f;
#pragma unroll
  for (int t = 0; t < 8; t++) {
    v[t] = ((const float4*)p)[lane + t * 64];
    m = fmaxf(m, fmaxf(fmaxf(v[t].x, v[t].y), fmaxf(v[t].z, v[t].w)));
  }
#pragma unroll
  for (int off = 32; off; off >>= 1) m = fmaxf(m, __shfl_xor(m, off, 64));

  float s = 0.f;
#pragma unroll
  for (int t = 0; t < 8; t++) {
    v[t].x = expf(v[t].x - m); v[t].y = expf(v[t].y - m);
    v[t].z = expf(v[t].z - m); v[t].w = expf(v[t].w - m);
    s += (v[t].x + v[t].y) + (v[t].z + v[t].w);
  }
#pragma unroll
  for (int off = 32; off; off >>= 1) s += __shfl_xor(s, off, 64);
  float inv = 1.0f / s;

#pragma unroll
  for (int t = 0; t < 8; t++) {
    bf16x4 o;
    o.x = (__bf16)(v[t].x * inv); o.y = (__bf16)(v[t].y * inv);
    o.z = (__bf16)(v[t].z * inv); o.w = (__bf16)(v[t].w * inv);
    *(bf16x4*)(q + (lane + t * 64) * 4) = o;
  }
}

// ---------------------------------------------------------------------------
extern "C" void kernel_launch(void* const* d_in, const int* in_sizes, int n_in,
                              void* d_out, int out_size, void* d_ws, size_t ws_size,
                              hipStream_t stream)
{
  (void)in_sizes; (void)n_in; (void)out_size; (void)ws_size;
  const float* x     = (const float*)d_in[0];
  const float* blade = (const float*)d_in[1];
  const float* w_q   = (const float*)d_in[2];
  const float* w_k   = (const float*)d_in[3];
  const float* w_v   = (const float*)d_in[4];
  const float* w_o   = (const float*)d_in[5];
  float* out = (float*)d_out;

  // --- fixed aliased workspace plan (peak 234,881,024 B; ws >= 256 MB) -----
  char* base = (char*)d_ws;
  __bf16* wbo   = (__bf16*)(base);                  //  16.78 MB [1024,8192]
  __bf16* vT    = (__bf16*)(base + 16777216);       //   8.39 MB [1024,4096]
  __bf16* qkmh  = (__bf16*)(base + 25165824);       //  37.75 MB [4096,4608]
  __bf16* qkml  = (__bf16*)(base + 62914560);       //  37.75 MB
  char* scr = base + 100663296;
  // phase 1 (aliases Pf region):
  __bf16* xh    = (__bf16*)(scr);                   //   8.39 MB [4096,1024]
  __bf16* xl    = (__bf16*)(scr + 8388608);         //   8.39 MB
  __bf16* wbqkh = (__bf16*)(scr + 16777216);        //   9.44 MB [4608,1024]
  __bf16* wbqkl = (__bf16*)(scr + 26214400);        //   9.44 MB
  __bf16* wbv   = (__bf16*)(scr + 35651584);        //   2.10 MB [1024,1024]
  // phase 2/3:
  float*  Pf    = (float*)(scr);                    //  67.11 MB [4,2048,2048]
  __bf16* A2    = (__bf16*)(scr + 67108864);        //  33.55 MB [2048,8192]
  float*  Part  = (float*)(scr + 100663296);        //  33.55 MB [4,2048,1024]

  dim3 blk(256);
  const float scale = 0.04419417382415922f;  // 1/sqrt(512)

  // --- phase 1: prep + projections ----------------------------------------
  prep2<<<10752, blk, 0, stream>>>(x, blade, w_q, w_k, w_v, w_o,
                                   xh, xl, wbqkh, wbqkl, wbv, wbo);

  // qkm = [q | km] hi/lo: [4096,1024] x [4608,1024]^T -> [4096,4608]
  gemm_split<2><<<dim3(36, 32, 1), blk, 0, stream>>>(
      xh, xl, 1024, 0, wbqkh, wbqkl, 1024, 0, qkmh, qkml, 4608, 0, 1024, 1.f);

  // vT = wbv * xh^T : [1024,1024] x [4096,1024]^T -> [1024,4096] bf16
  gemm_bf16<3><<<dim3(32, 8, 1), blk, 0, stream>>>(
      wbv, 1024, 0, xh, 1024, 0, vT, 4096, 0, 1024, 1.f);

  // --- phase 2/3: attention + O-projection per batch -----------------------
  for (int b = 0; b < 2; b++) {
    const __bf16* qh_b  = qkmh + (size_t)b * 2048 * 4608;
    const __bf16* ql_b  = qkml + (size_t)b * 2048 * 4608;
    const __bf16* kmh_b = qh_b + 4096;   // km cols 4096..4607, ldb 4608
    const __bf16* kml_b = ql_b + 4096;

    for (int h0 = 0; h0 < 8; h0 += 4) {
      // scores -> Pf [z,2048,2048] f32 (z = head in group)
      gemm_split<0><<<dim3(16, 16, 4), blk, 0, stream>>>(
          qh_b + h0 * 512, ql_b + h0 * 512, 4608, 512,
          kmh_b, kml_b, 4608, 0,
          Pf, nullptr, 2048, (long long)2048 * 2048, 512, scale);
      // softmax in place: bf16 P into Pf rows (row stride 4096 bf16 units)
      softmax_wave<<<4 * 2048 / 4, blk, 0, stream>>>(Pf);
      // PV: P [z,2048,2048] * vT_b^T -> A2 cols (h0+z)*1024
      gemm_bf16<3><<<dim3(8, 16, 4), blk, 0, stream>>>(
          (const __bf16*)Pf, 4096, (long long)2048 * 4096,
          vT + (size_t)b * 2048, 4096, 0,
          A2 + (size_t)h0 * 1024, 8192, 1024, 2048, 1.f);
    }

    // O-proj: A2 [2048,8192] x wbo [1024,8192]^T, split-K=4 -> partials
    gemm_bf16<0><<<dim3(8, 16, 4), blk, 0, stream>>>(
        A2, 8192, 2048, wbo, 8192, 2048,
        Part, 1024, (long long)2048 * 1024, 2048, 1.f);
    reduce4<<<2048, blk, 0, stream>>>(Part, out + (size_t)b * 2048 * 1024,
                                      2048 * 1024);
  }
}